// Round 6
// baseline (365.967 us; speedup 1.0000x reference)
//
#include <hip/hip_runtime.h>
#include <math.h>

#define C_     512
#define HW_    196    // 14*14
#define B_     10
#define P_     49
#define K_     50176  // 512*2*49
#define K4_    12544  // K_/4
#define NCLS   1000
#define NT     8      // classes per block-group in cla partial
#define NG     125    // class groups (NCLS/NT)
#define KCH    8      // K-chunks (split-K)
#define KC4_   1568   // K4_/KCH

// native vector type for __builtin_nontemporal_load (HIP_vector_type is a
// struct and the builtin rejects it)
typedef float vfloat4 __attribute__((ext_vector_type(4)));

// ws layout (floats): xcat[250880] | pool[5120] | conv_part[8*1960]
//                     | cla_part[8*5000] | cnt[125 ints]

// ---------------------------------------------------------------------------
// Kernel 1 "prep": blocks [0,980) build x_cat; [980,2260) maxpool; [2260,2340)
// conv-mask partials; block 2340 zeroes the split-K arrival counters.
// ---------------------------------------------------------------------------
__global__ __launch_bounds__(256) void prep_kernel(
    const float* __restrict__ x, const int* __restrict__ index_dy,
    const float* __restrict__ cw,
    float* __restrict__ xcat, float* __restrict__ pool,
    float* __restrict__ conv_part, int* __restrict__ cnt) {
  unsigned blk = blockIdx.x;
  if (blk < 980u) {
    // ---- build_xcat: fused 2x2 avgpool + odd-sample transpose/gather ----
    unsigned t = blk * 256u + threadIdx.x;   // 0 .. 250879
    unsigned n = t / K_;
    unsigned col = t % K_;
    unsigned b, c, h, w;
    if (col < 25088u) {          // unswap: xp[2n] flattened (c,h,w)
      b = 2u * n;
      c = col / 49u;
      unsigned hw = col % 49u;
      h = hw / 7u;  w = hw % 7u;
    } else {                     // reordered: F[i*49+idx], F[w*3584+c*7+h]=xp
      unsigned q = col - 25088u;
      unsigned i = q / 49u, j = q % 49u;
      unsigned jj = (unsigned)index_dy[(2u * n + 1u) * 49u + j];
      unsigned p = i * 49u + jj;
      w = p / 3584u;
      unsigned rem = p % 3584u;
      c = rem / 7u;  h = rem % 7u;
      b = 2u * n + 1u;
    }
    const float* xb = x + ((b * C_ + c) * 14u + 2u * h) * 14u + 2u * w;
    float2 r0 = *(const float2*)(xb);
    float2 r1 = *(const float2*)(xb + 14);
    xcat[t] = 0.25f * (r0.x + r0.y + r1.x + r1.y);
  } else if (blk < 2260u) {
    // ---- maxpool over HW per (b,c): one wave each, float4 loads ----
    int lb = (int)blk - 980;
    int wid = lb * 4 + (int)(threadIdx.x >> 6);   // 0..5119
    int lane = threadIdx.x & 63;
    const float4* xr = (const float4*)(x + (size_t)wid * HW_);
    float m = -INFINITY;
    if (lane < 49) {              // 49 float4 = 196 floats
      float4 v = xr[lane];
      m = fmaxf(fmaxf(v.x, v.y), fmaxf(v.z, v.w));
    }
    #pragma unroll
    for (int off = 32; off > 0; off >>= 1) m = fmaxf(m, __shfl_xor(m, off, 64));
    if (lane == 0) pool[wid] = m;
  } else if (blk < 2340u) {
    // ---- conv-mask partials: block = (b, 64-channel group g) ----
    int lb = (int)blk - 2260;     // 0..79
    int b = lb / 8, g = lb % 8;
    int t = threadIdx.x;
    if (t < HW_) {
      const float* xb = x + ((size_t)b * C_ + g * 64u) * HW_ + t;
      float a0 = 0.f, a1 = 0.f;
      #pragma unroll 8
      for (int c = 0; c < 64; c += 2) {
        a0 += cw[g * 64 + c] * xb[c * HW_];
        a1 += cw[g * 64 + c + 1] * xb[(c + 1) * HW_];
      }
      conv_part[(g * B_ + b) * HW_ + t] = a0 + a1;
    }
  } else {
    // ---- zero split-K arrival counters (ws is poisoned 0xAA each call) ----
    if (threadIdx.x < NG) cnt[threadIdx.x] = 0;
  }
}

// ---------------------------------------------------------------------------
// Kernel 2 "main2": blocks [0,1000) cla split-K partials (8 classes x 1/8 K
// each) with fused atomic-counter epilogue (last arrival per class-group sums
// the 8 partials + sigmoid); [1000,1500) swap_gemm; block 1500 mask finish.
// W loads are nontemporal (each W line touched exactly once -> don't evict
// xcat from L2).
// ---------------------------------------------------------------------------
__global__ __launch_bounds__(256) void main2_kernel(
    const float* __restrict__ xcat, const float* __restrict__ pool,
    const float* __restrict__ W, const float* __restrict__ Ws,
    const float* __restrict__ conv_part, const float* __restrict__ cb,
    float* __restrict__ cla_part, int* __restrict__ cnt,
    float* __restrict__ out) {
  __shared__ float red[4][NT][5];
  unsigned blk = blockIdx.x;
  int t = threadIdx.x;
  if (blk < 1000u) {
    // ---- cla partial: classes [nb,nb+8), K4 range [kbase, kbase+1568) ----
    int kc = (int)blk / NG;          // 0..7
    int g  = (int)blk % NG;          // class group
    int nb = g * NT;                 // 0..992
    int kbase = kc * KC4_;
    float acc[NT][5];
    #pragma unroll
    for (int a = 0; a < NT; ++a)
      #pragma unroll
      for (int m = 0; m < 5; ++m) acc[a][m] = 0.f;
    const float4* X4 = (const float4*)xcat;
    const vfloat4* W4 = (const vfloat4*)W;
    for (int k4 = kbase + t; k4 < kbase + KC4_; k4 += 256) {
      float4 xv[5];
      #pragma unroll
      for (int m = 0; m < 5; ++m) xv[m] = X4[m * K4_ + k4];
      #pragma unroll
      for (int a = 0; a < NT; ++a) {
        vfloat4 wv = __builtin_nontemporal_load(&W4[(size_t)(nb + a) * K4_ + k4]);
        #pragma unroll
        for (int m = 0; m < 5; ++m)
          acc[a][m] += wv.x * xv[m].x + wv.y * xv[m].y +
                       wv.z * xv[m].z + wv.w * xv[m].w;
      }
    }
    #pragma unroll
    for (int off = 32; off > 0; off >>= 1)
      #pragma unroll
      for (int a = 0; a < NT; ++a)
        #pragma unroll
        for (int m = 0; m < 5; ++m)
          acc[a][m] += __shfl_xor(acc[a][m], off, 64);
    int wv = t >> 6, lane = t & 63;
    if (lane == 0)
      #pragma unroll
      for (int a = 0; a < NT; ++a)
        #pragma unroll
        for (int m = 0; m < 5; ++m) red[wv][a][m] = acc[a][m];
    __syncthreads();
    // partial write + fused epilogue: all 40 writer lanes are in wave 0, so
    // one wave-level __threadfence gives release ordering for all of them.
    if (t < NT * 5) {
      int a = t / 5, m = t % 5;
      float s = red[0][a][m] + red[1][a][m] + red[2][a][m] + red[3][a][m];
      cla_part[kc * 5000 + m * NCLS + nb + a] = s;
    }
    __threadfence();                       // release (device scope)
    int old = 0;
    if (t == 0) old = atomicAdd(&cnt[g], 1);
    old = __shfl(old, 0, 64);              // broadcast within wave 0
    if (old == KCH - 1 && t < NT * 5) {
      __threadfence();                     // acquire (device scope)
      int a = t / 5, m = t % 5;
      float s = 0.f;
      #pragma unroll
      for (int kc2 = 0; kc2 < KCH; ++kc2)
        s += cla_part[kc2 * 5000 + m * NCLS + nb + a];
      out[m * NCLS + nb + a] = 1.f / (1.f + expf(-s));
    }
  } else if (blk < 1500u) {
    // ---- swap_gemm: out_swap = pool @ Ws^T, one wave per column ----
    int lb = (int)blk - 1000;
    int wid = lb * 4 + (t >> 6);   // 0..1999
    int lane = t & 63;
    const float4* swr = (const float4*)(Ws + (size_t)wid * C_);
    const float4* p4 = (const float4*)pool;
    float acc[B_];
    #pragma unroll
    for (int b = 0; b < B_; ++b) acc[b] = 0.f;
    #pragma unroll
    for (int u = 0; u < 2; ++u) {
      float4 v = swr[lane + 64 * u];
      #pragma unroll
      for (int b = 0; b < B_; ++b) {
        float4 p = p4[b * (C_ / 4) + lane + 64 * u];
        acc[b] += v.x * p.x + v.y * p.y + v.z * p.z + v.w * p.w;
      }
    }
    #pragma unroll
    for (int off = 32; off > 0; off >>= 1)
      #pragma unroll
      for (int b = 0; b < B_; ++b) acc[b] += __shfl_xor(acc[b], off, 64);
    if (lane == 0)
      #pragma unroll
      for (int b = 0; b < B_; ++b) out[5000 + b * 2 * NCLS + wid] = acc[b];
  } else {
    // ---- mask finish: 2x2 pool of conv partials + tanh (490 outputs) ----
    for (int t0 = t; t0 < B_ * P_; t0 += 256) {
      int b = t0 / P_, p = t0 % P_;
      int i = p / 7, j = p % 7;
      int q00 = (2 * i) * 14 + 2 * j;
      float s = 0.f;
      #pragma unroll
      for (int g = 0; g < 8; ++g) {
        const float* cp = conv_part + (g * B_ + b) * HW_;
        s += cp[q00] + cp[q00 + 1] + cp[q00 + 14] + cp[q00 + 15];
      }
      out[25000 + t0] = tanhf(0.25f * s + cb[0]);
    }
  }
}

// ---------------------------------------------------------------------------
extern "C" void kernel_launch(void* const* d_in, const int* in_sizes, int n_in,
                              void* d_out, int out_size, void* d_ws, size_t ws_size,
                              hipStream_t stream) {
  const float* x  = (const float*)d_in[0];   // [10,512,14,14]
  const float* cw = (const float*)d_in[1];   // [1,512,1,1]
  const float* cb = (const float*)d_in[2];   // [1]
  const float* Wc = (const float*)d_in[3];   // [1000, 50176]
  const float* Ws = (const float*)d_in[4];   // [2000, 512]
  const int*  idx = (const int*)d_in[5];     // [10,49] int32
  float* out = (float*)d_out;                // 5000 | 20000 | 490

  float* xcat      = (float*)d_ws;             // 250880
  float* pool      = xcat + 5 * K_;            // 5120
  float* conv_part = pool + B_ * C_;           // 8*1960 = 15680
  float* cla_part  = conv_part + 8 * B_ * HW_; // 8*5000 = 40000
  int*   cnt       = (int*)(cla_part + KCH * 5000); // 125 ints

  prep_kernel<<<2341, 256, 0, stream>>>(x, idx, cw, xcat, pool, conv_part, cnt);
  main2_kernel<<<1501, 256, 0, stream>>>(xcat, pool, Wc, Ws, conv_part, cb,
                                         cla_part, cnt, out);
}

// Round 7
// 291.731 us; speedup vs baseline: 1.2545x; 1.2545x over previous
//
#include <hip/hip_runtime.h>
#include <math.h>

#define C_     512
#define HW_    196    // 14*14
#define B_     10
#define P_     49
#define K_     50176  // 512*2*49
#define K4_    12544  // K_/4
#define NCLS   1000
#define NT     8      // classes per block-group in cla partial
#define NG     125    // class groups (NCLS/NT)
#define KCH    8      // K-chunks (split-K)
#define KC4_   1568   // K4_/KCH

// native vector type for __builtin_nontemporal_load (HIP_vector_type is a
// struct and the builtin rejects it)
typedef float vfloat4 __attribute__((ext_vector_type(4)));

// ws layout (floats): xcat[250880] | pool[5120] | conv_part[8*1960] | cla_part[8*5000]

// NOTE (R6 lesson): do NOT fuse the split-K reduction into main2 with a
// per-block device-scope __threadfence + atomic counter. On gfx950 the
// device-scope fence forces per-XCD L2 writeback/invalidate; 1000 blocks of
// that took main2 from ~35us to ~140us (740 GB/s, 9% peak). Separate tiny
// finish kernel is the right structure.

// ---------------------------------------------------------------------------
// Kernel 1 "prep": blocks [0,980) build x_cat; [980,2260) maxpool; [2260,2340)
// conv-mask partial sums over 64-channel groups.
// ---------------------------------------------------------------------------
__global__ __launch_bounds__(256) void prep_kernel(
    const float* __restrict__ x, const int* __restrict__ index_dy,
    const float* __restrict__ cw,
    float* __restrict__ xcat, float* __restrict__ pool,
    float* __restrict__ conv_part) {
  unsigned blk = blockIdx.x;
  if (blk < 980u) {
    // ---- build_xcat: fused 2x2 avgpool + odd-sample transpose/gather ----
    unsigned t = blk * 256u + threadIdx.x;   // 0 .. 250879
    unsigned n = t / K_;
    unsigned col = t % K_;
    unsigned b, c, h, w;
    if (col < 25088u) {          // unswap: xp[2n] flattened (c,h,w)
      b = 2u * n;
      c = col / 49u;
      unsigned hw = col % 49u;
      h = hw / 7u;  w = hw % 7u;
    } else {                     // reordered: F[i*49+idx], F[w*3584+c*7+h]=xp
      unsigned q = col - 25088u;
      unsigned i = q / 49u, j = q % 49u;
      unsigned jj = (unsigned)index_dy[(2u * n + 1u) * 49u + j];
      unsigned p = i * 49u + jj;
      w = p / 3584u;
      unsigned rem = p % 3584u;
      c = rem / 7u;  h = rem % 7u;
      b = 2u * n + 1u;
    }
    const float* xb = x + ((b * C_ + c) * 14u + 2u * h) * 14u + 2u * w;
    float2 r0 = *(const float2*)(xb);
    float2 r1 = *(const float2*)(xb + 14);
    xcat[t] = 0.25f * (r0.x + r0.y + r1.x + r1.y);
  } else if (blk < 2260u) {
    // ---- maxpool over HW per (b,c): one wave each, float4 loads ----
    int lb = (int)blk - 980;
    int wid = lb * 4 + (int)(threadIdx.x >> 6);   // 0..5119
    int lane = threadIdx.x & 63;
    const float4* xr = (const float4*)(x + (size_t)wid * HW_);
    float m = -INFINITY;
    if (lane < 49) {              // 49 float4 = 196 floats
      float4 v = xr[lane];
      m = fmaxf(fmaxf(v.x, v.y), fmaxf(v.z, v.w));
    }
    #pragma unroll
    for (int off = 32; off > 0; off >>= 1) m = fmaxf(m, __shfl_xor(m, off, 64));
    if (lane == 0) pool[wid] = m;
  } else {
    // ---- conv-mask partials: block = (b, 64-channel group g) ----
    int lb = (int)blk - 2260;     // 0..79
    int b = lb / 8, g = lb % 8;
    int t = threadIdx.x;
    if (t < HW_) {
      const float* xb = x + ((size_t)b * C_ + g * 64u) * HW_ + t;
      float a0 = 0.f, a1 = 0.f;
      #pragma unroll 8
      for (int c = 0; c < 64; c += 2) {
        a0 += cw[g * 64 + c] * xb[c * HW_];
        a1 += cw[g * 64 + c + 1] * xb[(c + 1) * HW_];
      }
      conv_part[(g * B_ + b) * HW_ + t] = a0 + a1;
    }
  }
}

// ---------------------------------------------------------------------------
// Kernel 2 "main2": blocks [0,1000) cla split-K partials (8 classes x 1/8 K
// each); [1000,1500) swap_gemm; block 1500 mask finish.
// W loads are nontemporal (each W line touched exactly once -> don't evict
// xcat from L2).
// ---------------------------------------------------------------------------
__global__ __launch_bounds__(256) void main2_kernel(
    const float* __restrict__ xcat, const float* __restrict__ pool,
    const float* __restrict__ W, const float* __restrict__ Ws,
    const float* __restrict__ conv_part, const float* __restrict__ cb,
    float* __restrict__ cla_part, float* __restrict__ out) {
  __shared__ float red[4][NT][5];
  unsigned blk = blockIdx.x;
  int t = threadIdx.x;
  if (blk < 1000u) {
    // ---- cla partial: classes [nb,nb+8), K4 range [kbase, kbase+1568) ----
    int kc = (int)blk / NG;          // 0..7
    int nb = ((int)blk % NG) * NT;   // 0..992
    int kbase = kc * KC4_;
    float acc[NT][5];
    #pragma unroll
    for (int a = 0; a < NT; ++a)
      #pragma unroll
      for (int m = 0; m < 5; ++m) acc[a][m] = 0.f;
    const float4* X4 = (const float4*)xcat;
    const vfloat4* W4 = (const vfloat4*)W;
    for (int k4 = kbase + t; k4 < kbase + KC4_; k4 += 256) {
      float4 xv[5];
      #pragma unroll
      for (int m = 0; m < 5; ++m) xv[m] = X4[m * K4_ + k4];
      #pragma unroll
      for (int a = 0; a < NT; ++a) {
        vfloat4 wv = __builtin_nontemporal_load(&W4[(size_t)(nb + a) * K4_ + k4]);
        #pragma unroll
        for (int m = 0; m < 5; ++m)
          acc[a][m] += wv.x * xv[m].x + wv.y * xv[m].y +
                       wv.z * xv[m].z + wv.w * xv[m].w;
      }
    }
    #pragma unroll
    for (int off = 32; off > 0; off >>= 1)
      #pragma unroll
      for (int a = 0; a < NT; ++a)
        #pragma unroll
        for (int m = 0; m < 5; ++m)
          acc[a][m] += __shfl_xor(acc[a][m], off, 64);
    int wv = t >> 6, lane = t & 63;
    if (lane == 0)
      #pragma unroll
      for (int a = 0; a < NT; ++a)
        #pragma unroll
        for (int m = 0; m < 5; ++m) red[wv][a][m] = acc[a][m];
    __syncthreads();
    if (t < NT * 5) {
      int a = t / 5, m = t % 5;
      float s = red[0][a][m] + red[1][a][m] + red[2][a][m] + red[3][a][m];
      cla_part[kc * 5000 + m * NCLS + nb + a] = s;
    }
  } else if (blk < 1500u) {
    // ---- swap_gemm: out_swap = pool @ Ws^T, one wave per column ----
    int lb = (int)blk - 1000;
    int wid = lb * 4 + (t >> 6);   // 0..1999
    int lane = t & 63;
    const float4* swr = (const float4*)(Ws + (size_t)wid * C_);
    const float4* p4 = (const float4*)pool;
    float acc[B_];
    #pragma unroll
    for (int b = 0; b < B_; ++b) acc[b] = 0.f;
    #pragma unroll
    for (int u = 0; u < 2; ++u) {
      float4 v = swr[lane + 64 * u];
      #pragma unroll
      for (int b = 0; b < B_; ++b) {
        float4 p = p4[b * (C_ / 4) + lane + 64 * u];
        acc[b] += v.x * p.x + v.y * p.y + v.z * p.z + v.w * p.w;
      }
    }
    #pragma unroll
    for (int off = 32; off > 0; off >>= 1)
      #pragma unroll
      for (int b = 0; b < B_; ++b) acc[b] += __shfl_xor(acc[b], off, 64);
    if (lane == 0)
      #pragma unroll
      for (int b = 0; b < B_; ++b) out[5000 + b * 2 * NCLS + wid] = acc[b];
  } else {
    // ---- mask finish: 2x2 pool of conv partials + tanh (490 outputs) ----
    for (int t0 = t; t0 < B_ * P_; t0 += 256) {
      int b = t0 / P_, p = t0 % P_;
      int i = p / 7, j = p % 7;
      int q00 = (2 * i) * 14 + 2 * j;
      float s = 0.f;
      #pragma unroll
      for (int g = 0; g < 8; ++g) {
        const float* cp = conv_part + (g * B_ + b) * HW_;
        s += cp[q00] + cp[q00 + 1] + cp[q00 + 14] + cp[q00 + 15];
      }
      out[25000 + t0] = tanhf(0.25f * s + cb[0]);
    }
  }
}

// ---------------------------------------------------------------------------
// Kernel 3: sum the 8 split-K partials + sigmoid.
// ---------------------------------------------------------------------------
__global__ __launch_bounds__(256) void finish_kernel(
    const float* __restrict__ cla_part, float* __restrict__ out) {
  int i = blockIdx.x * 256 + threadIdx.x;
  if (i < 5 * NCLS) {
    float s = 0.f;
    #pragma unroll
    for (int kc = 0; kc < KCH; ++kc) s += cla_part[kc * 5000 + i];
    out[i] = 1.f / (1.f + expf(-s));
  }
}

// ---------------------------------------------------------------------------
extern "C" void kernel_launch(void* const* d_in, const int* in_sizes, int n_in,
                              void* d_out, int out_size, void* d_ws, size_t ws_size,
                              hipStream_t stream) {
  const float* x  = (const float*)d_in[0];   // [10,512,14,14]
  const float* cw = (const float*)d_in[1];   // [1,512,1,1]
  const float* cb = (const float*)d_in[2];   // [1]
  const float* Wc = (const float*)d_in[3];   // [1000, 50176]
  const float* Ws = (const float*)d_in[4];   // [2000, 512]
  const int*  idx = (const int*)d_in[5];     // [10,49] int32
  float* out = (float*)d_out;                // 5000 | 20000 | 490

  float* xcat      = (float*)d_ws;             // 250880
  float* pool      = xcat + 5 * K_;            // 5120
  float* conv_part = pool + B_ * C_;           // 8*1960 = 15680
  float* cla_part  = conv_part + 8 * B_ * HW_; // 8*5000 = 40000

  prep_kernel<<<2340, 256, 0, stream>>>(x, idx, cw, xcat, pool, conv_part);
  main2_kernel<<<1501, 256, 0, stream>>>(xcat, pool, Wc, Ws, conv_part, cb,
                                         cla_part, out);
  finish_kernel<<<20, 256, 0, stream>>>(cla_part, out);
}